// Round 2
// baseline (257.217 us; speedup 1.0000x reference)
//
#include <hip/hip_runtime.h>

// out[b][i][j] = (j == indices[i]) ? grad[b][i] : 0
// grad (8,4096) f32, indices (4096,) int32, out (8,4096,2048) f32 = 256 MiB.
// Pure write-stream; floor = 268 MB / 6.5 TB/s ~= 41 us (+ the harness's
// ~164 us 1 GiB re-poison fill included in dur_us).
//
// R6: fill-style GLOBAL SLIDING WINDOW. R4/R5 gave each block a private
// 256 KiB region (1024 concurrent regions, waves hopping at 8 KiB stride)
// -> fragmented per-channel write streams, DRAM row thrash, ~3 TB/s.
// fillBufferAligned proves the winning shape: grid-stride, where at any
// instant the WHOLE GRID writes one contiguous ~8 MiB sliding window
// (dense row-buffer-hit bursts per channel, 6.5 TB/s).
//
// 2048 blocks x 256 threads = 524288 threads (32 waves/CU, one round).
// Thread owns f32x4 slot gtid; iteration i stores slot i*524288 + gtid.
// row = i*1024 + (gtid>>9) is BLOCK-UNIFORM -> idx/grad are scalar loads;
// column c4 = gtid & 511 is loop-invariant. Next row's (idx, g) prefetched
// before the current store, so scalar-load latency never exposes.

#define ROWS_PER_B 4096
#define NEWDIM     2048
#define F4_PER_ROW (NEWDIM / 4)        // 512
#define NTHREADS   524288              // 2048 blocks * 256 threads
#define ITERS      32                  // 16.8M f4 slots / 524288

typedef float f32x4 __attribute__((ext_vector_type(4)));

__global__ __launch_bounds__(256)
void ReduceMaxGrad_53833120088407_kernel(const float* __restrict__ grad,
                                         const int*  __restrict__ indices,
                                         float*      __restrict__ out) {
    const int gtid     = blockIdx.x * 256 + threadIdx.x;  // f4-slot in window 0
    const int c4       = gtid & (F4_PER_ROW - 1);         // thread's f4 column (fixed)
    const int row_base = gtid >> 9;                       // block-uniform, 0..1023
    const int c4x4     = c4 << 2;                         // first element owned

    f32x4* o = (f32x4*)out + gtid;

    int   idx = indices[row_base & (ROWS_PER_B - 1)];     // row for iter 0
    float g   = grad[row_base];

#pragma unroll
    for (int i = 0; i < ITERS; ++i) {
        int   nidx = 0;
        float ng   = 0.0f;
        if (i + 1 < ITERS) {                              // prefetch next row
            const int nrow = (i + 1) * 1024 + row_base;   // block-uniform
            nidx = indices[nrow & (ROWS_PER_B - 1)];
            ng   = grad[nrow];
        }
        const int c = idx - c4x4;                         // in [0,3] iff owned
        f32x4 v;
        v.x = (c == 0) ? g : 0.0f;
        v.y = (c == 1) ? g : 0.0f;
        v.z = (c == 2) ? g : 0.0f;
        v.w = (c == 3) ? g : 0.0f;
        o[(size_t)i * NTHREADS] = v;                      // contiguous 8 MiB/iter
        idx = nidx; g = ng;
    }
}

extern "C" void kernel_launch(void* const* d_in, const int* in_sizes, int n_in,
                              void* d_out, int out_size, void* d_ws, size_t ws_size,
                              hipStream_t stream) {
    const float* grad    = (const float*)d_in[0];   // (8, 4096) f32
    const int*   indices = (const int*)d_in[1];     // (4096,) int32
    float*       out     = (float*)d_out;           // (8, 4096, 2048) f32

    ReduceMaxGrad_53833120088407_kernel<<<dim3(2048), dim3(256), 0, stream>>>(
        grad, indices, out);
}

// Round 3
// 228.781 us; speedup vs baseline: 1.1243x; 1.1243x over previous
//
#include <hip/hip_runtime.h>

// out[b][i][j] = (j == indices[i]) ? grad[b][i] : 0
// grad (8,4096) f32, indices (4096,) int32 (jax x64 off -> int32), out (8,4096,2048) f32.
//
// R7: memset + scatter. Only 32768 of the 67M output floats are non-zero.
// R4/R5/R6 (three radically different full-stream store kernels) were all
// identical in dur_us -> stop hand-writing the zero stream. Enqueue the
// runtime's own fillBufferAligned (proven 6.55 TB/s on this exact buffer
// class) via hipMemsetAsync, then scatter the 32768 non-zeros:
//   out[t*2048 + indices[t & 4095]] = grad[t]      (t = b*4096+i)
// Scatter traffic ~= 32768 * 64B lines ~= 2 MiB -> ~5 us. Total stream work
// ~= 41 us fill + 5 us scatter = best possible byte count for this output.
// This is also a decomposition probe: if dur_us does NOT drop, the previous
// kernels were already at fill rate and dur_us is harness-floor-dominated.

#define ROWS_PER_B 4096
#define NEWDIM     2048

__global__ __launch_bounds__(512)
void ReduceMaxGrad_53833120088407_scatter(const float* __restrict__ grad,
                                          const int*  __restrict__ indices,
                                          float*      __restrict__ out) {
    const int t = blockIdx.x * 512 + threadIdx.x;     // 0..32767 = b*4096 + i
    const int i = t & (ROWS_PER_B - 1);
    const int idx = indices[i];                       // coalesced across lanes
    const float g = grad[t];                          // coalesced across lanes
    out[(size_t)t * NEWDIM + idx] = g;                // one dword per row
}

extern "C" void kernel_launch(void* const* d_in, const int* in_sizes, int n_in,
                              void* d_out, int out_size, void* d_ws, size_t ws_size,
                              hipStream_t stream) {
    const float* grad    = (const float*)d_in[0];   // (8, 4096) f32
    const int*   indices = (const int*)d_in[1];     // (4096,) int32
    float*       out     = (float*)d_out;           // (8, 4096, 2048) f32

    // Zero the whole output with the runtime's optimized fill (~41 us),
    // then scatter the 32768 non-zeros (~5 us). Same-stream -> ordered.
    hipMemsetAsync(d_out, 0, (size_t)out_size, stream);

    const int n_rows = in_sizes[0] * (n_in > 0 ? 1 : 1); // 8*4096 = 32768 rows total
    ReduceMaxGrad_53833120088407_scatter<<<dim3(32768 / 512), dim3(512), 0, stream>>>(
        grad, indices, out);
}